// Round 6
// baseline (5916.730 us; speedup 1.0000x reference)
//
#include <hip/hip_runtime.h>

// ============================================================================
// MYLSTM: functional-basis LSTM, T=49, BATCH=2048, UNITS=DIM=256, QN=9.
//
// Round 6 restructure: B-STATIONARY recurrent kernel.
//   Evidence (r4/r5): FETCH scales with #wgs at constant ~60% L2 hit -> the
//   per-step WP stream can never be L2-resident. Fix: partition the 1024 gate
//   cols across wgs so each wg's B-slice (256 cols x 256 k = 128 KB) lives in
//   LDS, loaded ONCE. Per-step B traffic: zero.
//   - wg = (32 batch rows) x (64 units x 4 gates). grid 256 = 64 rowgroups x
//     4 unit-slices, 512 thr (8 waves: 2 mtiles x 4 unit-subtiles).
//   - K=256 (c-part). x-part hoisted: xp = X @ Wx precomputed per chunk by
//     xproj_k (one GEMM launch per chunk, 128-row tiles).
//   - Per-step c exchange among the 4 wgs of a row-group: double-buffered
//     cbuf + per-group flag (release fence + atomicAdd / relaxed spin +
//     acquire fence). Cooperative launch ONLY for co-residency guarantee;
//     NO grid.sync. Fences can't evict anything hot: B is in LDS.
//   - Group members share an XCD via blockIdx = us*64+rg (locality only).
//   - s stored to S (nt); proj_k (unchanged) does h = tanh(S_t @ U_t) after.
// ============================================================================

typedef unsigned short u16;
typedef unsigned int u32;
typedef __attribute__((ext_vector_type(8))) short bf16x8;
typedef __attribute__((ext_vector_type(4))) float f32x4;

#define T_STEPS 49
#define OUT_ROW 12544 // 49*256

__device__ __forceinline__ u16 f2b(float f) {
  u32 u = __float_as_uint(f);
  u += 0x7fffu + ((u >> 16) & 1u); // RNE
  return (u16)(u >> 16);
}
__device__ __forceinline__ float b2f(u16 h) { return __uint_as_float(((u32)h) << 16); }
__device__ __forceinline__ float sigm(float z) { return 1.0f / (1.0f + __expf(-z)); }
__device__ __forceinline__ float tanh_f(float z) {
  float e = __expf(-2.0f * fabsf(z));
  float r = (1.0f - e) / (1.0f + e); // overflow-safe: e->0 => 1
  return __builtin_copysignf(r, z);
}

// ---------------------------------------------------------------------------
// Pack weights (r0 layout): WcP[n][k]=W_g[k][u], WxP[n][k]=W_g[256+k][u],
// n = g*256+u. Also zero cbuf[0] (1 MB) and the 64 group flags (re-done every
// launch so graph replays start clean).
__global__ void pack_w(const float* __restrict__ Wf, const float* __restrict__ Wi,
                       const float* __restrict__ Wc, const float* __restrict__ Wo,
                       u16* __restrict__ WcP, u16* __restrict__ WxP,
                       u16* __restrict__ cbuf0, u32* __restrict__ flags) {
  int n = blockIdx.x, k = threadIdx.x;
  int g = n >> 8, u = n & 255;
  const float* W = (g == 0) ? Wf : (g == 1) ? Wi : (g == 2) ? Wc : Wo;
  WcP[n * 256 + k] = f2b(W[k * 256 + u]);
  WxP[n * 256 + k] = f2b(W[(256 + k) * 256 + u]);
  ((u32*)cbuf0)[n * 256 + k] = 0u; // 1024*256 u32 == 1 MB == cbuf[0]
  if (n == 0 && k < 64) flags[k] = 0u;
}

// ---------------------------------------------------------------------------
// U pack: UP[t][jp][j] = sum_q Q[j*2304 + jp*9 + q] * B(t,q), bf16.
__global__ void pack_u(const float* __restrict__ Q, u16* __restrict__ UP) {
  int bx = blockIdx.x;
  int t = bx >> 8, jp = bx & 255, j = threadIdx.x;
  const float* q = Q + j * 2304 + jp * 9;
  float tv = (float)t / 48.0f;
  float acc = q[0];
  const float SQ2 = 1.41421356237f;
#pragma unroll
  for (int i = 1; i <= 4; ++i) {
    float ang = 6.283185307179586f * (float)i * tv;
    acc += SQ2 * (sinf(ang) * q[2 * i - 1] + cosf(ang) * q[2 * i]);
  }
  UP[t * 65536 + jp * 256 + j] = f2b(acc);
}

// ---------------------------------------------------------------------------
// xproj: xp[(tt*2048 + b)*1024 + n] = x[b, t0+tt, :] @ WxP[n, :].
// grid ct*16 blocks x 512 thr; block = (tt, 128-row tile). B held in regs
// (64 KB/wave read once); A re-read from LDS per col-tile (cheap).
__global__ __launch_bounds__(512) void xproj_k(const float* __restrict__ x,
                                               const u16* __restrict__ WxP,
                                               u16* __restrict__ xp,
                                               int t0, int ct) {
  __shared__ u16 aLds[128][264]; // +8 pad breaks 512B-stride bank aliasing
  int tid = threadIdx.x;
  int bx = blockIdx.x;
  int tt = bx >> 4;
  int t = t0 + tt;
  int b0 = (bx & 15) * 128;
  // stage 128 rows x 256 k fp32 -> bf16 (x read once: nt)
#pragma unroll
  for (int it = 0; it < 16; ++it) {
    int flat = it * 512 + tid;
    int r = flat >> 6, kc = (flat & 63) * 4;
    const f32x4 v = __builtin_nontemporal_load(
        (const f32x4*)&x[((size_t)(b0 + r) * T_STEPS + t) * 256 + kc]);
    u16 tmp[4] = {f2b(v.x), f2b(v.y), f2b(v.z), f2b(v.w)};
    *(uint2*)&aLds[r][kc] = *(uint2*)tmp;
  }
  __syncthreads();
  int w = tid >> 6, l = tid & 63, lane15 = l & 15, quad = l >> 4;
#pragma unroll 1
  for (int ctl = 0; ctl < 8; ++ctl) {
    int col = w * 128 + ctl * 16 + lane15;
    const u16* bp = WxP + (size_t)col * 256 + quad * 8;
    bf16x8 bf[8];
#pragma unroll
    for (int ks = 0; ks < 8; ++ks) bf[ks] = *(const bf16x8*)(bp + ks * 32);
#pragma unroll 1
    for (int rt = 0; rt < 8; ++rt) {
      f32x4 acc = {0.f, 0.f, 0.f, 0.f};
#pragma unroll
      for (int ks = 0; ks < 8; ++ks) {
        bf16x8 af = *(const bf16x8*)&aLds[rt * 16 + lane15][ks * 32 + quad * 8];
        acc = __builtin_amdgcn_mfma_f32_16x16x32_bf16(af, bf[ks], acc, 0, 0, 0);
      }
#pragma unroll
      for (int i = 0; i < 4; ++i)
        __builtin_nontemporal_store(
            f2b(acc[i]),
            &xp[((size_t)tt * 2048 + b0 + rt * 16 + quad * 4 + i) * 1024 + col]);
    }
  }
}

// ---------------------------------------------------------------------------
// Recurrent kernel (cooperative, NO grid.sync). 256 wgs x 512 thr, 1 wg/CU.
// blockIdx = us*64 + rg: rg = row-group (32 rows), us = unit-slice (64 units).
// B-slice (256 cols x 256 k, XOR-swizzled) in LDS, loaded once.
// Per step: stage c_t (16 KB) -> LDS, GEMM (K=256), in-reg elementwise,
// write c_{t+1} slice + S, flag handshake with the 3 sibling wgs.
__global__ __launch_bounds__(512) void rec_k(const u16* __restrict__ WcP,
                                             const u16* __restrict__ xp,
                                             u16* __restrict__ cbuf,
                                             u32* __restrict__ flags,
                                             u16* __restrict__ S,
                                             int tA, int tB) {
  __shared__ u16 B_lds[256 * 256]; // [col][k] 128 KB, byte ^= (col&7)<<4
  __shared__ u16 c_lds[32 * 256];  // [row][k] 16 KB,  byte ^= (row&7)<<4
  int tid = threadIdx.x;
  int bxv = blockIdx.x;
  int us = bxv >> 6, rg = bxv & 63;
  int b0 = rg * 32, u0 = us * 64;
  int w = tid >> 6, l = tid & 63, lane15 = l & 15, quad = l >> 4;
  int mtw = w >> 2, wu = w & 3;      // wave: M-tile (0/1), unit-subtile (0..3)
  int u_own = u0 + wu * 16 + lane15; // lane's unit (all 4 gates)

  // ---- load B slice into LDS once: col_local = g*64 + uu <- WcP row g*256+u0+uu
  for (int idx = tid; idx < 8192; idx += 512) { // 8192 x 16B
    int cl = idx >> 5, j = idx & 31;
    int n = (cl >> 6) * 256 + u0 + (cl & 63);
    bf16x8 v = *(const bf16x8*)&WcP[(size_t)n * 256 + j * 8];
    *(bf16x8*)((char*)B_lds + cl * 512 + ((j * 16) ^ ((cl & 7) << 4))) = v;
  }
  __syncthreads();

  float creg[4];
  const u32 sw_l15 = (u32)((lane15 & 7) << 4);

#pragma unroll 1
  for (int t = tA; t < tB; ++t) {
    int tloc = t - tA;
    // prefetch xp (x-part of gate preactivations) for this step: 16 u16/lane.
    u16 xpv[4][4];
#pragma unroll
    for (int i = 0; i < 4; ++i) {
      const u16* xb = xp + ((size_t)tloc * 2048 + b0 + mtw * 16 + quad * 4 + i) * 1024 + u_own;
#pragma unroll
      for (int g = 0; g < 4; ++g) xpv[i][g] = __builtin_nontemporal_load(xb + g * 256);
    }
    // ---- wait for c_t from sibling wgs (t=0: cbuf[0] zeroed by pack_w)
    if (t > 0) {
      if (tid == 0) {
        while (__hip_atomic_load(&flags[rg], __ATOMIC_RELAXED,
                                 __HIP_MEMORY_SCOPE_AGENT) < (u32)(4 * t))
          __builtin_amdgcn_s_sleep(2);
      }
      __syncthreads();
      __threadfence(); // acquire: invalidate stale c lines (B is in LDS, immune)
    }
    // ---- stage c_t -> c_lds (32 rows x 512 B, swizzled), 32 B/thread
    {
      int row = tid >> 4, j = tid & 15;
      const u16* src = cbuf + (size_t)(t & 1) * 524288 + (size_t)(b0 + row) * 256 + j * 16;
      bf16x8 v0 = *(const bf16x8*)(src);
      bf16x8 v1 = *(const bf16x8*)(src + 8);
      char* dst = (char*)c_lds + row * 512;
      u32 swr = (u32)((row & 7) << 4);
      *(bf16x8*)(dst + ((j * 32) ^ swr)) = v0;
      *(bf16x8*)(dst + ((j * 32 + 16) ^ swr)) = v1;
    }
    __syncthreads();
    // creg init at chunk start (c_t for own unit, from staged tile)
    if (t == tA) {
#pragma unroll
      for (int i = 0; i < 4; ++i) {
        int r = mtw * 16 + quad * 4 + i;
        creg[i] = b2f(*(const u16*)((char*)c_lds + r * 512 +
                                    ((u_own * 2) ^ ((r & 7) << 4))));
      }
    }
    // ---- gate GEMM: A from c_lds (held), B from B_lds; 4 gates x 8 ks
    bf16x8 af[8];
#pragma unroll
    for (int ks = 0; ks < 8; ++ks)
      af[ks] = *(const bf16x8*)((char*)c_lds + (mtw * 16 + lane15) * 512 +
                                ((ks * 64 + quad * 16) ^ sw_l15));
    f32x4 a0 = {0.f, 0.f, 0.f, 0.f}, a1 = a0, a2 = a0, a3 = a0;
#pragma unroll
    for (int ks = 0; ks < 8; ++ks) {
      u32 ko = (u32)(ks * 64 + quad * 16) ^ sw_l15;
      const char* bb = (const char*)B_lds + (wu * 16 + lane15) * 512;
      a0 = __builtin_amdgcn_mfma_f32_16x16x32_bf16(af[ks], *(const bf16x8*)(bb + 0 * 32768 + ko), a0, 0, 0, 0);
      a1 = __builtin_amdgcn_mfma_f32_16x16x32_bf16(af[ks], *(const bf16x8*)(bb + 1 * 32768 + ko), a1, 0, 0, 0);
      a2 = __builtin_amdgcn_mfma_f32_16x16x32_bf16(af[ks], *(const bf16x8*)(bb + 2 * 32768 + ko), a2, 0, 0, 0);
      a3 = __builtin_amdgcn_mfma_f32_16x16x32_bf16(af[ks], *(const bf16x8*)(bb + 3 * 32768 + ko), a3, 0, 0, 0);
    }
    // ---- elementwise in-register; write c_{t+1} slice + s
    u16* cdst = cbuf + (size_t)((t + 1) & 1) * 524288;
#pragma unroll
    for (int i = 0; i < 4; ++i) {
      int r = mtw * 16 + quad * 4 + i;
      float zf = a0[i] + b2f(xpv[i][0]);
      float zi = a1[i] + b2f(xpv[i][1]);
      float zg = a2[i] + b2f(xpv[i][2]);
      float zo = a3[i] + b2f(xpv[i][3]);
      float f = sigm(zf), ii = sigm(zi), gg = sigm(zg), o = tanh_f(zo);
      float cn = ii * gg + f * creg[i];
      creg[i] = cn;
      cdst[(size_t)(b0 + r) * 256 + u_own] = f2b(cn);
      float s = o * tanh_f(cn);
      __builtin_nontemporal_store(f2b(s),
          &S[((size_t)t * 2048 + b0 + r) * 256 + u_own]);
    }
    // ---- signal step done (release)
    if (t + 1 < T_STEPS) {
      __threadfence(); // release: drain c stores to agent scope
      __syncthreads();
      if (tid == 0)
        __hip_atomic_fetch_add(&flags[rg], 1u, __ATOMIC_RELAXED,
                               __HIP_MEMORY_SCOPE_AGENT);
    }
  }
}

// ---------------------------------------------------------------------------
// Proj kernel: h = tanh(S_t @ U_t), per t: M=2048, N=256, K=256. (r5, proven)
__global__ __launch_bounds__(512) void proj_k(const u16* __restrict__ S,
                                              const u16* __restrict__ UP,
                                              float* __restrict__ out) {
  int bx = blockIdx.x;
  int t = bx >> 5, mt = bx & 31;
  int m0 = mt * 64;
  int tid = threadIdx.x;
  int w = tid >> 6, l = tid & 63, lane15 = l & 15, quad = l >> 4;
  const u16* Sbase = S + ((size_t)t * 2048 + m0) * 256;
  const u16* Ubase = UP + (size_t)t * 65536;
#pragma unroll
  for (int rtp = 0; rtp < 2; ++rtp) {
    bf16x8 af[2][8];
#pragma unroll
    for (int h = 0; h < 2; ++h)
#pragma unroll
      for (int ks = 0; ks < 8; ++ks)
        af[h][ks] = *(const bf16x8*)(Sbase + (rtp * 32 + h * 16 + lane15) * 256 +
                                     ks * 32 + quad * 8);
#pragma unroll
    for (int ct = 0; ct < 2; ++ct) {
      int col = w * 32 + ct * 16 + lane15;
      const u16* up = Ubase + col * 256 + quad * 8;
      bf16x8 bf[8];
#pragma unroll
      for (int ks = 0; ks < 8; ++ks) bf[ks] = *(const bf16x8*)(up + ks * 32);
#pragma unroll
      for (int h = 0; h < 2; ++h) {
        f32x4 acc = {0.f, 0.f, 0.f, 0.f};
#pragma unroll
        for (int ks = 0; ks < 8; ++ks)
          acc = __builtin_amdgcn_mfma_f32_16x16x32_bf16(af[h][ks], bf[ks], acc, 0, 0, 0);
#pragma unroll
        for (int i = 0; i < 4; ++i) {
          int b = m0 + rtp * 32 + h * 16 + quad * 4 + i;
          __builtin_nontemporal_store(
              tanh_f(acc[i]), &out[(size_t)b * OUT_ROW + t * 256 + col]);
        }
      }
    }
  }
}

// ---------------------------------------------------------------------------
extern "C" void kernel_launch(void* const* d_in, const int* in_sizes, int n_in,
                              void* d_out, int out_size, void* d_ws, size_t ws_size,
                              hipStream_t stream) {
  const float* x = (const float*)d_in[0];
  const float* Wf = (const float*)d_in[1];
  const float* Wi = (const float*)d_in[2];
  const float* Wc = (const float*)d_in[3];
  const float* Wo = (const float*)d_in[4];
  const float* Q = (const float*)d_in[5];
  float* out = (float*)d_out;

  char* p = (char*)d_ws;
  u16* WcP = (u16*)p;   p += (size_t)1024 * 256 * 2;      // 512 KB
  u16* WxP = (u16*)p;   p += (size_t)1024 * 256 * 2;      // 512 KB
  u16* UP = (u16*)p;    p += (size_t)49 * 256 * 256 * 2;  // 6.13 MB
  u16* cbuf = (u16*)p;  p += (size_t)2 * 2048 * 256 * 2;  // 2 MB (double buf)
  u32* flags = (u32*)p; p += 4096;                        // 64 group flags
  u16* Sb = (u16*)p;    p += (size_t)49 * 2048 * 256 * 2; // 51.4 MB
  u16* xpb = (u16*)p;
  size_t used = (size_t)(p - (char*)d_ws);
  size_t rem = (ws_size > used) ? (ws_size - used) : 0;
  const size_t perT = (size_t)2048 * 1024 * 2; // 4 MB per timestep of xp
  int CT = (int)(rem / perT);
  if (CT > 49) CT = 49;
  if (CT < 1) CT = 1;

  pack_w<<<dim3(1024), dim3(256), 0, stream>>>(Wf, Wi, Wc, Wo, WcP, WxP, cbuf, flags);
  pack_u<<<dim3(49 * 256), dim3(256), 0, stream>>>(Q, UP);

  for (int t0 = 0; t0 < T_STEPS; t0 += CT) {
    int cc = (T_STEPS - t0 < CT) ? (T_STEPS - t0) : CT;
    xproj_k<<<dim3(cc * 16), dim3(512), 0, stream>>>(x, WxP, xpb, t0, cc);
    int tBv = t0 + cc;
    void* kargs[] = {(void*)&WcP, (void*)&xpb, (void*)&cbuf, (void*)&flags,
                     (void*)&Sb, (void*)&t0, (void*)&tBv};
    hipLaunchCooperativeKernel((const void*)rec_k, dim3(256), dim3(512), kargs,
                               0, stream);
  }
  proj_k<<<dim3(49 * 32), dim3(512), 0, stream>>>(Sb, UP, out);
}